// Round 16
// baseline (49.014 us; speedup 1.0000x reference)
//
#include <hip/hip_runtime.h>
#include <hip/hip_bf16.h>

#define C_ 384
#define B_ 16
#define H_ 56
#define W_ 56
#define WROW_ 8              // u32 weight-pairs per ky row in wpk
#define SPSZ_ 4944           // 2*2448 + 48 pad u32 (keeps all A-reads in-bounds)

typedef _Float16 f16x8 __attribute__((ext_vector_type(8)));
typedef float    f32x4 __attribute__((ext_vector_type(4)));

// ---- folded weight value for (c, py, px), px<13 ----
__device__ __forceinline__ float foldw(int c, int py, int px,
    const float* lk, const float* w5, const float* w7a, const float* w7b,
    const float* w3a, const float* w3b, const float* w3c, const float* sc)
{
    int dy = py - 6, dx = px - 6;
    float a = sc[0] * lk[c * 169 + py * 13 + px];
#define ADDBR(Wp, K, R, SI)                                               \
    {                                                                     \
        const int half = ((K) - 1) / 2;                                   \
        if (dy % (R) == 0 && dx % (R) == 0) {                             \
            int iy = dy / (R), ix = dx / (R);                             \
            if (iy >= -half && iy <= half && ix >= -half && ix <= half)   \
                a += sc[SI] * Wp[c * (K) * (K) + (iy + half) * (K) + (ix + half)]; \
        }                                                                 \
    }
    ADDBR(w5,  5, 1, 1)
    ADDBR(w7a, 7, 1, 2)
    ADDBR(w7b, 7, 2, 3)
    ADDBR(w3a, 3, 3, 4)
    ADDBR(w3b, 3, 4, 5)
    ADDBR(w3c, 3, 5, 6)
#undef ADDBR
    return a;
}

// wpk[c][ky][8 u32] = f16 pairs (w0..w12, 0,0,0); bias[c] = summed BN shifts.
__global__ void build_weights_kernel(
    const float* __restrict__ lk, const float* __restrict__ obn,
    const float* __restrict__ w5, const float* __restrict__ w7a,
    const float* __restrict__ w7b, const float* __restrict__ w3a,
    const float* __restrict__ w3b, const float* __restrict__ w3c,
    const float* __restrict__ brbn,
    unsigned* __restrict__ wpk, float* __restrict__ bias)
{
    int c = blockIdx.x;
    int t = threadIdx.x;

    float sc[7], sh[7];
    {
        float g = obn[c], b = obn[C_ + c], m = obn[2 * C_ + c], v = obn[3 * C_ + c];
        float s = g * rsqrtf(v + 1e-5f);
        sc[0] = s; sh[0] = b - m * s;
    }
#pragma unroll
    for (int i = 0; i < 6; ++i) {
        float g = brbn[(i * 4 + 0) * C_ + c], b = brbn[(i * 4 + 1) * C_ + c];
        float m = brbn[(i * 4 + 2) * C_ + c], v = brbn[(i * 4 + 3) * C_ + c];
        float s = g * rsqrtf(v + 1e-5f);
        sc[i + 1] = s; sh[i + 1] = b - m * s;
    }

    if (t < 13 * WROW_) {
        int ky = t / WROW_, pp = t % WROW_;
        int kx0 = 2 * pp, kx1 = 2 * pp + 1;
        float w0 = (kx0 < 13) ? foldw(c, ky, kx0, lk, w5, w7a, w7b, w3a, w3b, w3c, sc) : 0.f;
        float w1 = (kx1 < 13) ? foldw(c, ky, kx1, lk, w5, w7a, w7b, w3a, w3b, w3c, sc) : 0.f;
        _Float16 h0 = (_Float16)w0, h1 = (_Float16)w1;
        unsigned u = ((unsigned)__builtin_bit_cast(unsigned short, h1) << 16)
                   |  (unsigned)__builtin_bit_cast(unsigned short, h0);
        wpk[c * 13 * WROW_ + t] = u;
    }
    if (t == 0) {
        float s = 0.f;
#pragma unroll
        for (int i = 0; i < 7; ++i) s += sh[i];
        bias[c] = s;
    }
}

// MFMA depthwise conv. Block = 2 planes (batches 2bg, 2bg+1) of channel c.
// Per ky: OUT[16x16] += A[m][k] * B_ky[k][n]; A = input rows (M = 2 planes x
// 8 rows), B_ky = banded Toeplitz of weight row ky (B[k][n] = w[ky][k-n]).
// R15: B-fragments PINNED in VGPRs via opaque asm (R13/R14's VGPR=52 proved
// the compiler was re-reading bf from LDS every MFMA -> LDS-pipe-bound).
__global__ __launch_bounds__(256, 4) void dwconv13_mfma(
    const float* __restrict__ x, const unsigned* __restrict__ wpk,
    const float* __restrict__ bias, float* __restrict__ out)
{
    __shared__ unsigned sP[SPSZ_];      // 2 planes, 68 rows x 36 u32 + pad
    __shared__ unsigned sQ[13 * 24];    // padded weight rows
    __shared__ unsigned sB[13 * 256];   // B frags: [ky][lane][4 u32]

    const int bid = blockIdx.x;
    const int c   = bid % C_;
    const int bg  = bid / C_;     // 0..7
    const int b0  = bg * 2;
    const int t   = threadIdx.x;

    // ---- Phase 0: issue global loads; fill sQ (all 312); zero sP. ----
    unsigned vv[13]; int dd[13];
#pragma unroll
    for (int k = 0; k < 13; ++k) {
        int slot = t + k * 256;
        if (k < 12 || slot < 3136) {
            int p  = slot / 1568, rem = slot - p * 1568;
            int iy = rem / 28,    pr  = rem - iy * 28;
            const float* xp = x + ((size_t)((b0 + p) * C_ + c)) * (H_ * W_);
            float2 v = *(const float2*)(xp + iy * W_ + pr * 2);
            _Float16 h0 = (_Float16)v.x, h1 = (_Float16)v.y;   // RNE
            vv[k] = ((unsigned)__builtin_bit_cast(unsigned short, h1) << 16)
                  |  (unsigned)__builtin_bit_cast(unsigned short, h0);
            dd[k] = p * 2448 + (iy + 6) * 36 + 3 + pr;
        }
    }
#pragma unroll
    for (int k = 0; k < 2; ++k) {
        int s = t + k * 256;
        if (s < 13 * 24) {
            int ky = s / 24, t24 = s - ky * 24;
            unsigned q = 0;
            if (t24 >= 8 && t24 < 16) q = wpk[c * 104 + ky * 8 + (t24 - 8)];
            sQ[s] = q;
        }
    }
    {
        uint4 z = make_uint4(0u, 0u, 0u, 0u);
        uint4* s4 = (uint4*)sP;
#pragma unroll
        for (int k = 0; k < 5; ++k) {
            int slot = t + k * 256;
            if (k < 4 || slot < SPSZ_ / 4) s4[slot] = z;
        }
    }
    __syncthreads();

    // ---- Phase 1: commit staged rows; build B fragments. ----
#pragma unroll
    for (int k = 0; k < 13; ++k) {
        int slot = t + k * 256;
        if (k < 12 || slot < 3136) sP[dd[k]] = vv[k];
    }
#pragma unroll
    for (int k = 0; k < 13; ++k) {
        int e   = t + k * 256;            // 13*256 = 3328 exact
        int ky  = e >> 8, rem = e & 255;
        int ln  = rem >> 2, j = rem & 3;
        int g   = ln >> 4,  n = ln & 15;
        int q   = 16 + 8 * g + 2 * j - n;     // f16 pair start in padded row
        const unsigned* Q = sQ + ky * 24;
        unsigned v = (n & 1) ? ((Q[(q - 1) >> 1] >> 16) | (Q[(q + 1) >> 1] << 16))
                             : Q[q >> 1];
        sB[e] = v;
    }
    __syncthreads();

    // ---- Phase 2: compute. Wave w owns col-tile x0 = 16w, loops 7 row-tiles.
    const float bv  = bias[c];
    const int lane = t & 63;
    const int wv   = t >> 6;          // 0..3
    const int x0   = wv * 16;
    const int g    = lane >> 4, n = lane & 15;
    const int r8   = lane & 7,  pp = (lane >> 3) & 1;

    // B fragments: load once, then PIN in VGPRs (opaque asm breaks any
    // LDS-rematerialization; values must stay register-resident).
    f16x8 bf[13];
#pragma unroll
    for (int ky = 0; ky < 13; ++ky) {
        uint4 u = *(const uint4*)(sB + ky * 256 + lane * 4);
        asm volatile("" : "+v"(u.x), "+v"(u.y), "+v"(u.z), "+v"(u.w));
        bf[ky] = __builtin_bit_cast(f16x8, u);
    }

    const int aBase = pp * 2448 + r8 * 36 + x0 / 2 + 4 * g;
    const int xo = x0 + n;

#pragma unroll
    for (int ty = 0; ty < 7; ++ty) {
        f32x4 d0 = { bv, bv, bv, bv };
        f32x4 d1 = { 0.f, 0.f, 0.f, 0.f };
        int base = aBase + (8 * ty) * 36;
        uint4 ua = *(const uint4*)(sP + base);
#pragma unroll
        for (int ky = 0; ky < 13; ++ky) {
            uint4 un;
            if (ky < 12) un = *(const uint4*)(sP + base + (ky + 1) * 36);
            f16x8 a = __builtin_bit_cast(f16x8, ua);
            if (ky & 1) d1 = __builtin_amdgcn_mfma_f32_16x16x32_f16(a, bf[ky], d1, 0, 0, 0);
            else        d0 = __builtin_amdgcn_mfma_f32_16x16x32_f16(a, bf[ky], d0, 0, 0, 0);
            if (ky < 12) ua = un;
        }
        d0 = d0 + d1;
        if (xo < W_) {
#pragma unroll
            for (int r = 0; r < 4; ++r) {
                int m  = 4 * g + r;           // D row = M index
                int p2 = m >> 3, rr = m & 7;
                out[((size_t)((b0 + p2) * C_ + c)) * (H_ * W_)
                    + (8 * ty + rr) * W_ + xo] = d0[r];
            }
        }
    }
}

extern "C" void kernel_launch(void* const* d_in, const int* in_sizes, int n_in,
                              void* d_out, int out_size, void* d_ws, size_t ws_size,
                              hipStream_t stream) {
    const float* x    = (const float*)d_in[0];
    const float* lk   = (const float*)d_in[1];
    const float* obn  = (const float*)d_in[2];
    const float* w5   = (const float*)d_in[3];
    const float* w7a  = (const float*)d_in[4];
    const float* w7b  = (const float*)d_in[5];
    const float* w3a  = (const float*)d_in[6];
    const float* w3b  = (const float*)d_in[7];
    const float* w3c  = (const float*)d_in[8];
    const float* brbn = (const float*)d_in[9];
    float* out  = (float*)d_out;

    unsigned* wpk  = (unsigned*)d_ws;                  // 384*104 u32
    float*    bias = (float*)(wpk + C_ * 13 * WROW_);  // 384 floats

    hipLaunchKernelGGL(build_weights_kernel, dim3(C_), dim3(128), 0, stream,
                       lk, obn, w5, w7a, w7b, w3a, w3b, w3c, brbn, wpk, bias);

    hipLaunchKernelGGL(dwconv13_mfma, dim3((B_ / 2) * C_), dim3(256), 0, stream,
                       x, wpk, bias, out);
}

// Round 17
// 41.706 us; speedup vs baseline: 1.1752x; 1.1752x over previous
//
#include <hip/hip_runtime.h>
#include <hip/hip_bf16.h>

#define C_ 384
#define B_ 16
#define H_ 56
#define W_ 56
#define WROW_ 8              // u32 weight-pairs per ky row in wpk
#define SPSZ_ 4944           // 2*2448 + 48 pad u32 (keeps all A-reads in-bounds)

typedef _Float16 f16x8 __attribute__((ext_vector_type(8)));
typedef float    f32x4 __attribute__((ext_vector_type(4)));

// ---- folded weight value for (c, py, px), px<13 ----
__device__ __forceinline__ float foldw(int c, int py, int px,
    const float* lk, const float* w5, const float* w7a, const float* w7b,
    const float* w3a, const float* w3b, const float* w3c, const float* sc)
{
    int dy = py - 6, dx = px - 6;
    float a = sc[0] * lk[c * 169 + py * 13 + px];
#define ADDBR(Wp, K, R, SI)                                               \
    {                                                                     \
        const int half = ((K) - 1) / 2;                                   \
        if (dy % (R) == 0 && dx % (R) == 0) {                             \
            int iy = dy / (R), ix = dx / (R);                             \
            if (iy >= -half && iy <= half && ix >= -half && ix <= half)   \
                a += sc[SI] * Wp[c * (K) * (K) + (iy + half) * (K) + (ix + half)]; \
        }                                                                 \
    }
    ADDBR(w5,  5, 1, 1)
    ADDBR(w7a, 7, 1, 2)
    ADDBR(w7b, 7, 2, 3)
    ADDBR(w3a, 3, 3, 4)
    ADDBR(w3b, 3, 4, 5)
    ADDBR(w3c, 3, 5, 6)
#undef ADDBR
    return a;
}

// wpk[c][ky][8 u32] = f16 pairs (w0..w12, 0,0,0); bias[c] = summed BN shifts.
__global__ void build_weights_kernel(
    const float* __restrict__ lk, const float* __restrict__ obn,
    const float* __restrict__ w5, const float* __restrict__ w7a,
    const float* __restrict__ w7b, const float* __restrict__ w3a,
    const float* __restrict__ w3b, const float* __restrict__ w3c,
    const float* __restrict__ brbn,
    unsigned* __restrict__ wpk, float* __restrict__ bias)
{
    int c = blockIdx.x;
    int t = threadIdx.x;

    float sc[7], sh[7];
    {
        float g = obn[c], b = obn[C_ + c], m = obn[2 * C_ + c], v = obn[3 * C_ + c];
        float s = g * rsqrtf(v + 1e-5f);
        sc[0] = s; sh[0] = b - m * s;
    }
#pragma unroll
    for (int i = 0; i < 6; ++i) {
        float g = brbn[(i * 4 + 0) * C_ + c], b = brbn[(i * 4 + 1) * C_ + c];
        float m = brbn[(i * 4 + 2) * C_ + c], v = brbn[(i * 4 + 3) * C_ + c];
        float s = g * rsqrtf(v + 1e-5f);
        sc[i + 1] = s; sh[i + 1] = b - m * s;
    }

    if (t < 13 * WROW_) {
        int ky = t / WROW_, pp = t % WROW_;
        int kx0 = 2 * pp, kx1 = 2 * pp + 1;
        float w0 = (kx0 < 13) ? foldw(c, ky, kx0, lk, w5, w7a, w7b, w3a, w3b, w3c, sc) : 0.f;
        float w1 = (kx1 < 13) ? foldw(c, ky, kx1, lk, w5, w7a, w7b, w3a, w3b, w3c, sc) : 0.f;
        _Float16 h0 = (_Float16)w0, h1 = (_Float16)w1;
        unsigned u = ((unsigned)__builtin_bit_cast(unsigned short, h1) << 16)
                   |  (unsigned)__builtin_bit_cast(unsigned short, h0);
        wpk[c * 13 * WROW_ + t] = u;
    }
    if (t == 0) {
        float s = 0.f;
#pragma unroll
        for (int i = 0; i < 7; ++i) s += sh[i];
        bias[c] = s;
    }
}

// MFMA depthwise conv. Block = 2 planes (batches 2bg, 2bg+1) of channel c.
// Per ky: OUT[16x16] += A[m][k] * B_ky[k][n]; A = input rows (M = 2 planes x
// 8 rows), B_ky = banded Toeplitz of weight row ky (B[k][n] = w[ky][k-n]).
// R16: sB (13KB) deleted - bf computed per-lane from sQ via 5 consecutive
// u32 reads + variable-shift alignbit (identical for both lane parities).
// LDS 34.8 -> 21.1KB; launch_bounds(256,5) -> ~20 waves/CU to hide latency.
__global__ __launch_bounds__(256, 5) void dwconv13_mfma(
    const float* __restrict__ x, const unsigned* __restrict__ wpk,
    const float* __restrict__ bias, float* __restrict__ out)
{
    __shared__ unsigned sP[SPSZ_];      // 2 planes, 68 rows x 36 u32 + pad
    __shared__ unsigned sQ[320];        // 13 rows x 24 u32 + 8 pad (zeros)

    const int bid = blockIdx.x;
    const int c   = bid % C_;
    const int bg  = bid / C_;     // 0..7
    const int b0  = bg * 2;
    const int t   = threadIdx.x;

    // ---- Phase 0: issue global loads; fill sQ (all 320, pad=0); zero sP. ----
    unsigned vv[13]; int dd[13];
#pragma unroll
    for (int k = 0; k < 13; ++k) {
        int slot = t + k * 256;
        if (k < 12 || slot < 3136) {
            int p  = slot / 1568, rem = slot - p * 1568;
            int iy = rem / 28,    pr  = rem - iy * 28;
            const float* xp = x + ((size_t)((b0 + p) * C_ + c)) * (H_ * W_);
            float2 v = *(const float2*)(xp + iy * W_ + pr * 2);
            _Float16 h0 = (_Float16)v.x, h1 = (_Float16)v.y;   // RNE
            vv[k] = ((unsigned)__builtin_bit_cast(unsigned short, h1) << 16)
                  |  (unsigned)__builtin_bit_cast(unsigned short, h0);
            dd[k] = p * 2448 + (iy + 6) * 36 + 3 + pr;
        }
    }
#pragma unroll
    for (int k = 0; k < 2; ++k) {
        int s = t + k * 256;
        if (s < 320) {
            unsigned q = 0;
            if (s < 312) {
                int ky = s / 24, t24 = s - ky * 24;
                if (t24 >= 8 && t24 < 16) q = wpk[c * 104 + ky * 8 + (t24 - 8)];
            }
            sQ[s] = q;
        }
    }
    {
        uint4 z = make_uint4(0u, 0u, 0u, 0u);
        uint4* s4 = (uint4*)sP;
#pragma unroll
        for (int k = 0; k < 5; ++k) {
            int slot = t + k * 256;
            if (k < 4 || slot < SPSZ_ / 4) s4[slot] = z;
        }
    }
    __syncthreads();

    // ---- Phase 1: commit staged rows. ----
#pragma unroll
    for (int k = 0; k < 13; ++k) {
        int slot = t + k * 256;
        if (k < 12 || slot < 3136) sP[dd[k]] = vv[k];
    }
    __syncthreads();

    // ---- Phase 2: compute. Wave w owns col-tile x0 = 16w, loops 7 row-tiles.
    const float bv  = bias[c];
    const int lane = t & 63;
    const int wv   = t >> 6;          // 0..3
    const int x0   = wv * 16;
    const int g    = lane >> 4, n = lane & 15;
    const int r8   = lane & 7,  pp = (lane >> 3) & 1;

    // Per-lane B fragments from sQ: word_j = alignbit(Q[v0+j+1], Q[v0+j], sh)
    // with q0 = 16+8g-n, v0 = q0>>1, sh = (q0&1)*16 (both parities unified).
    const int q0 = 16 + 8 * g - n;
    const int v0 = q0 >> 1;
    const unsigned shb = (unsigned)(q0 & 1) * 16u;
    f16x8 bf[13];
#pragma unroll
    for (int ky = 0; ky < 13; ++ky) {
        const unsigned* Q = sQ + ky * 24 + v0;
        unsigned U0 = Q[0], U1 = Q[1], U2 = Q[2], U3 = Q[3], U4 = Q[4];
        uint4 u;
        u.x = __builtin_amdgcn_alignbit(U1, U0, shb);
        u.y = __builtin_amdgcn_alignbit(U2, U1, shb);
        u.z = __builtin_amdgcn_alignbit(U3, U2, shb);
        u.w = __builtin_amdgcn_alignbit(U4, U3, shb);
        bf[ky] = __builtin_bit_cast(f16x8, u);
    }

    const int aBase = pp * 2448 + r8 * 36 + x0 / 2 + 4 * g;
    const int xo = x0 + n;

#pragma unroll
    for (int ty = 0; ty < 7; ++ty) {
        f32x4 d0 = { bv, bv, bv, bv };
        f32x4 d1 = { 0.f, 0.f, 0.f, 0.f };
        int base = aBase + (8 * ty) * 36;
        uint4 ua = *(const uint4*)(sP + base);
#pragma unroll
        for (int ky = 0; ky < 13; ++ky) {
            uint4 un;
            if (ky < 12) un = *(const uint4*)(sP + base + (ky + 1) * 36);
            f16x8 a = __builtin_bit_cast(f16x8, ua);
            if (ky & 1) d1 = __builtin_amdgcn_mfma_f32_16x16x32_f16(a, bf[ky], d1, 0, 0, 0);
            else        d0 = __builtin_amdgcn_mfma_f32_16x16x32_f16(a, bf[ky], d0, 0, 0, 0);
            if (ky < 12) ua = un;
        }
        d0 = d0 + d1;
        if (xo < W_) {
#pragma unroll
            for (int r = 0; r < 4; ++r) {
                int m  = 4 * g + r;           // D row = M index
                int p2 = m >> 3, rr = m & 7;
                out[((size_t)((b0 + p2) * C_ + c)) * (H_ * W_)
                    + (8 * ty + rr) * W_ + xo] = d0[r];
            }
        }
    }
}

extern "C" void kernel_launch(void* const* d_in, const int* in_sizes, int n_in,
                              void* d_out, int out_size, void* d_ws, size_t ws_size,
                              hipStream_t stream) {
    const float* x    = (const float*)d_in[0];
    const float* lk   = (const float*)d_in[1];
    const float* obn  = (const float*)d_in[2];
    const float* w5   = (const float*)d_in[3];
    const float* w7a  = (const float*)d_in[4];
    const float* w7b  = (const float*)d_in[5];
    const float* w3a  = (const float*)d_in[6];
    const float* w3b  = (const float*)d_in[7];
    const float* w3c  = (const float*)d_in[8];
    const float* brbn = (const float*)d_in[9];
    float* out  = (float*)d_out;

    unsigned* wpk  = (unsigned*)d_ws;                  // 384*104 u32
    float*    bias = (float*)(wpk + C_ * 13 * WROW_);  // 384 floats

    hipLaunchKernelGGL(build_weights_kernel, dim3(C_), dim3(128), 0, stream,
                       lk, obn, w5, w7a, w7b, w3a, w3b, w3c, brbn, wpk, bias);

    hipLaunchKernelGGL(dwconv13_mfma, dim3((B_ / 2) * C_), dim3(256), 0, stream,
                       x, wpk, bias, out);
}